// Round 19
// baseline (177.716 us; speedup 1.0000x reference)
//
#include <hip/hip_runtime.h>

#define BS 16
#define NH 16
#define LQ 4096
#define DH 32

constexpr size_t OUT_ELEMS = (size_t)BS * NH * LQ * DH;   // 33,554,432
constexpr int HDE = NH * DH * DH;           // 16384
constexpr int NSPLIT = 8;                   // block owns 512 consecutive s
constexpr int NCH = 4;                      // 4 x 128-s windows per block

__device__ __forceinline__ void fma4(float4& a, float s, const float4& v) {
    a.x = fmaf(s, v.x, a.x);
    a.y = fmaf(s, v.y, a.y);
    a.z = fmaf(s, v.z, a.z);
    a.w = fmaf(s, v.w, a.w);
}

// ---------------- Kernel A: partial K@V — T14 async-STAGE split ----------------
// R18 probe verdict: kv's load pattern streams at >5 TB/s bare; the binder is
// the SERIAL per-window chain stage(900cyc cold-miss) -> barrier -> compute.
// Fix: issue window c+1's 8 plain loads into REGISTERS before compute(c);
// compute (~1100 cyc pure LDS+FMA) covers the miss latency; post-WAR-barrier
// ds_write consumes landed values (single vmcnt wait, already satisfied).
// Single LDS buffer, __syncthreads-only (proven), R17 swizzles verbatim
// (K[r][c] at slot c^((r>>2)&7); V[s][g] at slot g^(s&7)), R12 reduce verbatim.
template<int NCHT>
__global__ __launch_bounds__(256, 2) void kv_partial(const float* __restrict__ k,
                                                     const float* __restrict__ v,
                                                     float* __restrict__ part) {
    __shared__ float lds[8192];             // K[32][128] swz | V[128][32] swz; reduce reuses
    const int tid = threadIdx.x;
    const int w   = tid >> 6;
    const int l   = tid & 63;
    const int nsplit = 32 / NCHT;
    const int p  = blockIdx.x % nsplit;
    const int bh = blockIdx.x / nsplit;

    const int tw = tid & 31;
    const int sp = tid >> 5;                // 0..7: 16-s slice
    const int dg = tw >> 3;                 // 0..3
    const int eg = tw & 7;                  // 0..7
    const int d0 = dg << 3;                 // 8 rows

    const float* kb = k + (size_t)bh * DH * LQ;
    const float* vb = v + (size_t)bh * LQ * DH;
    float* kt = lds;                        // 4096 floats
    float* vt = lds + 4096;                 // 4096 floats

    // staging constants (R17-proven)
    const int kr   = tid >> 3;              // K row 0..31
    const int km   = tid & 7;               // chunk position
    const int kswz = (kr >> 2) & 7;
    const int vs   = tid >> 1;              // V row 0..127
    const int vh   = tid & 1;               // e-half
    const int vswz = vs & 7;

    float4 acc[8];
#pragma unroll
    for (int i = 0; i < 8; ++i) acc[i] = make_float4(0.f, 0.f, 0.f, 0.f);

    float4 kst[4], vst[4];

    // ---- prologue: stage window 0 ----
    {
        const int s0 = (p * NCHT) << 7;
#pragma unroll
        for (int j = 0; j < 4; ++j)
            kst[j] = *(const float4*)(kb + (size_t)kr * LQ + s0 + ((km + 8 * j) << 2));
#pragma unroll
        for (int j = 0; j < 4; ++j)
            vst[j] = *(const float4*)(vb + ((size_t)(s0 + vs) << 5) + (vh << 4) + (j << 2));
#pragma unroll
        for (int j = 0; j < 4; ++j)
            *(float4*)(kt + (kr << 7) + (((km + 8 * j) ^ kswz) << 2)) = kst[j];
#pragma unroll
        for (int j = 0; j < 4; ++j) {
            const int g = (vh << 2) + j;
            *(float4*)(vt + (vs << 5) + ((g ^ vswz) << 2)) = vst[j];
        }
        __syncthreads();                    // window 0 resident
    }

#pragma unroll
    for (int c = 0; c < NCHT; ++c) {
        // ---- issue window c+1's loads NOW: they fly during compute(c) ----
        if (c + 1 < NCHT) {
            const int s1 = (p * NCHT + c + 1) << 7;
#pragma unroll
            for (int j = 0; j < 4; ++j)
                kst[j] = *(const float4*)(kb + (size_t)kr * LQ + s1 + ((km + 8 * j) << 2));
#pragma unroll
            for (int j = 0; j < 4; ++j)
                vst[j] = *(const float4*)(vb + ((size_t)(s1 + vs) << 5) + (vh << 4) + (j << 2));
        }

        // ---- compute window c: pure LDS + FMA (covers load latency) ----
#pragma unroll
        for (int st = 0; st < 4; ++st) {
            const int cc = (sp << 2) + st;  // s-chunk 0..31 (4 s)
            float4 kq[8];
#pragma unroll
            for (int i = 0; i < 8; ++i) {
                const int r = d0 + i;
                kq[i] = *(const float4*)(kt + (r << 7) + ((cc ^ ((r >> 2) & 7)) << 2));
            }
#pragma unroll
            for (int u = 0; u < 4; ++u) {
                const int s = (cc << 2) + u;
                const float4 vu = *(const float4*)(vt + (s << 5) + ((eg ^ (s & 7)) << 2));
#pragma unroll
                for (int i = 0; i < 8; ++i) {
                    const float ks = (u == 0) ? kq[i].x
                                   : (u == 1) ? kq[i].y
                                   : (u == 2) ? kq[i].z : kq[i].w;
                    fma4(acc[i], ks, vu);
                }
            }
        }

        // ---- publish window c+1 (loads already landed) ----
        if (c + 1 < NCHT) {
            __syncthreads();                // WAR: all waves done reading window c
#pragma unroll
            for (int j = 0; j < 4; ++j)
                *(float4*)(kt + (kr << 7) + (((km + 8 * j) ^ kswz) << 2)) = kst[j];
#pragma unroll
            for (int j = 0; j < 4; ++j) {
                const int g = (vh << 2) + j;
                *(float4*)(vt + (vs << 5) + ((g ^ vswz) << 2)) = vst[j];
            }
            __syncthreads();                // window c+1 resident
        }
    }

    // ---- reduce (R12-proven): butterfly over sp-halves, then 4 waves via LDS ----
#pragma unroll
    for (int i = 0; i < 8; ++i) {
        acc[i].x += __shfl_xor(acc[i].x, 32);
        acc[i].y += __shfl_xor(acc[i].y, 32);
        acc[i].z += __shfl_xor(acc[i].z, 32);
        acc[i].w += __shfl_xor(acc[i].w, 32);
    }

    __syncthreads();                        // all staging reads done: reuse lds
    if (l < 32) {
        float* dst = lds + w * 1152 + l * 36;
#pragma unroll
        for (int i = 0; i < 8; ++i) *(float4*)(dst + (i << 2)) = acc[i];
    }
    __syncthreads();

    const int fdg = (tid >> 6) & 3;
    const int fi  = (tid >> 3) & 7;
    const int feg = tid & 7;
    const int off = (fdg * 8 + feg) * 36 + (fi << 2);
    float4 r0 = *(const float4*)(lds + off);
    const float4 r1 = *(const float4*)(lds + 1152 + off);
    const float4 r2 = *(const float4*)(lds + 2304 + off);
    const float4 r3 = *(const float4*)(lds + 3456 + off);
    r0.x = (r0.x + r1.x) + (r2.x + r3.x);
    r0.y = (r0.y + r1.y) + (r2.y + r3.y);
    r0.z = (r0.z + r1.z) + (r2.z + r3.z);
    r0.w = (r0.w + r1.w) + (r2.w + r3.w);
    *(float4*)(part + ((size_t)p * (BS * NH) + bh) * 1024 + (tid << 2)) = r0;
}

// ---------------- Kernel B1: reduce partials over p ----------------
__global__ __launch_bounds__(256) void reduce_p(const float* __restrict__ part,
                                                float* __restrict__ wts, int nsp) {
    const int gidx = blockIdx.x * 256 + threadIdx.x;   // b*16384 + h*1024+d*32+e
    float s = 0.f;
#pragma unroll 8
    for (int pp = 0; pp < nsp; ++pp)
        s += part[((size_t)pp << 18) + gidx];
    wts[gidx] = s * (1.0f / 64.0f);                    // / sqrt(4096)
}

// ---------------- Kernel B2: softmax over batch axis (in-place on wts) ----------------
__global__ __launch_bounds__(256) void softmax_b(float* __restrict__ wts) {
    const int idx = blockIdx.x * 256 + threadIdx.x;    // 0..16383

    float sc[BS];
#pragma unroll
    for (int b = 0; b < BS; ++b) sc[b] = wts[((size_t)b << 14) + idx];
    float m = sc[0];
#pragma unroll
    for (int b = 1; b < BS; ++b) m = fmaxf(m, sc[b]);
    float sum = 0.f;
#pragma unroll
    for (int b = 0; b < BS; ++b) { sc[b] = __expf(sc[b] - m); sum += sc[b]; }
    const float inv = 1.0f / sum;
#pragma unroll
    for (int b = 0; b < BS; ++b) wts[((size_t)b << 14) + idx] = sc[b] * inv;
}

// ---------------- Kernel C: out = Q @ W ----------------
__global__ __launch_bounds__(256, 2) void qw(const float* __restrict__ q,
                                             const float* __restrict__ wts,
                                             float* __restrict__ out) {
    __shared__ float qs[128 * 36];
    const int blk = blockIdx.x;
    const int bh  = blk >> 5;
    const int lt  = blk & 31;
    const int tid = threadIdx.x;

    const float* qbase = q + ((size_t)bh * LQ + lt * 128) * DH;

#pragma unroll
    for (int pp = 0; pp < 4; ++pp) {
        const int idx = pp * 256 + tid;           // float4 index 0..1023
        const int row = idx >> 3;
        const int c4  = idx & 7;
        const float4 t = *(const float4*)(qbase + idx * 4);
        *(float4*)(qs + row * 36 + c4 * 4) = t;
    }

    const int lsub = tid >> 3;                    // 0..31
    const int e0   = (tid & 7) << 2;

    const int b = bh >> 4, h = bh & 15;
    float4 Wf[32];
    const float* wbase = wts + ((size_t)b << 14) + ((size_t)h << 10) + e0;
#pragma unroll
    for (int d = 0; d < 32; ++d) Wf[d] = *(const float4*)(wbase + d * DH);

    __syncthreads();

    float* obase = out + ((size_t)bh * LQ + lt * 128) * DH;

#pragma unroll
    for (int r = 0; r < 4; ++r) {
        const int lr = lsub + r * 32;
        const float* qrow = qs + lr * 36;
        float4 acc = {0, 0, 0, 0};
#pragma unroll
        for (int d4 = 0; d4 < 32; d4 += 4) {
            const float4 qv = *(const float4*)(qrow + d4);
            fma4(acc, qv.x, Wf[d4 + 0]);
            fma4(acc, qv.y, Wf[d4 + 1]);
            fma4(acc, qv.z, Wf[d4 + 2]);
            fma4(acc, qv.w, Wf[d4 + 3]);
        }
        *(float4*)(obase + (size_t)lr * DH + e0) = acc;
    }
}

extern "C" void kernel_launch(void* const* d_in, const int* in_sizes, int n_in,
                              void* d_out, int out_size, void* d_ws, size_t ws_size,
                              hipStream_t stream) {
    const float* q = (const float*)d_in[0];
    const float* k = (const float*)d_in[1];
    const float* v = (const float*)d_in[2];
    float* out  = (float*)d_out;
    float* wts  = out + OUT_ELEMS;          // attn_weights region of d_out
    float* part = (float*)d_ws;             // 8 MB of partials (NSPLIT=8)

    kv_partial<NCH><<<BS * NH * NSPLIT, 256, 0, stream>>>(k, v, part);
    reduce_p<<<(BS * HDE) / 256, 256, 0, stream>>>(part, wts, NSPLIT);
    softmax_b<<<HDE / 256, 256, 0, stream>>>(wts);
    qw<<<BS * NH * (LQ / 128), 256, 0, stream>>>(q, wts, out);
}

// Round 20
// 141.107 us; speedup vs baseline: 1.2594x; 1.2594x over previous
//
#include <hip/hip_runtime.h>

#define BS 16
#define NH 16
#define LQ 4096
#define DH 32

constexpr size_t OUT_ELEMS = (size_t)BS * NH * LQ * DH;   // 33,554,432
constexpr int HDE = NH * DH * DH;           // 16384

__device__ __forceinline__ void fma4(float4& a, float s, const float4& v) {
    a.x = fmaf(s, v.x, a.x);
    a.y = fmaf(s, v.y, a.y);
    a.z = fmaf(s, v.z, a.z);
    a.w = fmaf(s, v.w, a.w);
}

// ---------------- Kernel A: partial K@V — 1-WAVE blocks, ZERO barriers ----------------
// R2-R19 invariant: every 4-wave barrier-synced structure = 95-104us with all
// pipes <25% at any occupancy/staging/tile. The never-removed element: the
// __syncthreads convoy (4 lockstep waves serialize each window's loaded-miss
// latency). Fix by construction: 64-thread blocks -> LDS is wave-private ->
// NO barriers anywhere. ~16-20 independent waves/CU; per-wave in-order LDS
// ops + alias analysis + sched_barrier(0) preserve stage->compute->restage
// ordering without any sync primitive.
// Per 32-s window: 8 plain coalesced loads (K rows 128B segments w/ source
// XOR swizzle csrc = cs ^ (r>>2); V rows linear) -> 8 LINEAR ds_write_b128
// (conflict-free) -> compute tile 4d x 8e, sp-halves (K read slot cc^dg:
// 2-way = free; V row-broadcast: free). shfl_xor(32) reduce (R12-proven),
// fully-coalesced direct partial store. No gll, no vmcnt asm, no barriers.
template<int NWIN>   // 32-s windows per block
__global__ __launch_bounds__(64) void kv_partial(const float* __restrict__ k,
                                                 const float* __restrict__ v,
                                                 float* __restrict__ part) {
    __shared__ float kt[1024];              // K[32 r][8 slots x4], swizzled content
    __shared__ float vt[1024];              // V[32 s][32 e], linear
    const int l  = threadIdx.x;
    const int nsplit = 128 / NWIN;          // block covers NWIN*32 s
    const int p  = blockIdx.x % nsplit;
    const int bh = blockIdx.x / nsplit;

    const int sp = l >> 5;                  // 0..1: 16-s half of each window
    const int dg = (l >> 2) & 7;            // 0..7: 4-row group
    const int eg = l & 3;                   // 0..3: 8-col group
    const int d0 = dg << 2;
    const int e0 = eg << 3;

    const float* kb = k + (size_t)bh * DH * LQ;
    const float* vb = v + (size_t)bh * LQ * DH;

    // staging constants: instr j covers rows/s 8j..8j+7; lane: row = 8j+(l>>3),
    // K stored-slot cs = l&7 holds source chunk cs ^ (r>>2) (involution with
    // the read-side slot = cc ^ dg, since r>>2 = dg for read rows).
    const int krow8 = l >> 3;               // row within 8-row group
    const int kcs   = l & 7;
    const int ksw   = l >> 5;               // (r>>2) = 2j + (l>>5)

    float4 acc[4][2];
#pragma unroll
    for (int i = 0; i < 4; ++i) {
        acc[i][0] = make_float4(0.f, 0.f, 0.f, 0.f);
        acc[i][1] = make_float4(0.f, 0.f, 0.f, 0.f);
    }

#pragma unroll
    for (int c = 0; c < NWIN; ++c) {
        const int wb = (p * NWIN + c) << 5; // window's 32-s base

        // ---- stage: 8 plain coalesced loads (deep MLP), 8 LINEAR ds_writes ----
        float4 kst[4], vst[4];
#pragma unroll
        for (int j = 0; j < 4; ++j) {
            const int r    = (j << 3) + krow8;
            const int csrc = kcs ^ (((j << 1) + ksw) & 7);
            kst[j] = *(const float4*)(kb + (size_t)r * LQ + wb + (csrc << 2));
        }
#pragma unroll
        for (int j = 0; j < 4; ++j) {
            const int s = (j << 3) + krow8;
            vst[j] = *(const float4*)(vb + ((size_t)(wb + s) << 5) + (kcs << 2));
        }
#pragma unroll
        for (int j = 0; j < 4; ++j) *(float4*)(kt + (j << 8) + (l << 2)) = kst[j];
#pragma unroll
        for (int j = 0; j < 4; ++j) *(float4*)(vt + (j << 8) + (l << 2)) = vst[j];
        __builtin_amdgcn_sched_barrier(0);  // compile-time fence: no reordering

        // ---- compute: pure LDS + FMA; wave-private, in-order vs the writes ----
#pragma unroll
        for (int st = 0; st < 4; ++st) {
            const int cc = (sp << 2) + st;  // chunk 0..7 (4 s each)
            float4 kq[4];
#pragma unroll
            for (int i = 0; i < 4; ++i)
                kq[i] = *(const float4*)(kt + ((d0 + i) << 5) + (((cc ^ dg) & 7) << 2));
#pragma unroll
            for (int u = 0; u < 4; ++u) {
                const int s = (cc << 2) + u;
                const float4 vu0 = *(const float4*)(vt + (s << 5) + e0);
                const float4 vu1 = *(const float4*)(vt + (s << 5) + e0 + 4);
#pragma unroll
                for (int i = 0; i < 4; ++i) {
                    const float ks = (u == 0) ? kq[i].x
                                   : (u == 1) ? kq[i].y
                                   : (u == 2) ? kq[i].z : kq[i].w;
                    fma4(acc[i][0], ks, vu0);
                    fma4(acc[i][1], ks, vu1);
                }
            }
        }
        __builtin_amdgcn_sched_barrier(0);  // keep next stage after these reads
    }

    // ---- reduce: butterfly over the two sp-halves (in-register, no LDS) ----
#pragma unroll
    for (int i = 0; i < 4; ++i)
#pragma unroll
        for (int h = 0; h < 2; ++h) {
            acc[i][h].x += __shfl_xor(acc[i][h].x, 32);
            acc[i][h].y += __shfl_xor(acc[i][h].y, 32);
            acc[i][h].z += __shfl_xor(acc[i][h].z, 32);
            acc[i][h].w += __shfl_xor(acc[i][h].w, 32);
        }

    // coalesced partial store: lane writes its half's columns (sp picks half
    // via ternary -- NOT runtime array index, rule #20). Per i: 8 x 128B segs.
    float* pb = part + ((size_t)p << 18) + ((size_t)bh << 10);
#pragma unroll
    for (int i = 0; i < 4; ++i) {
        const float4 wv = (sp == 0) ? acc[i][0] : acc[i][1];
        *(float4*)(pb + ((d0 + i) << 5) + e0 + (sp << 2)) = wv;
    }
}

// ---------------- Kernel B1: reduce partials over p (R12-proven) ----------------
__global__ __launch_bounds__(256) void reduce_p(const float* __restrict__ part,
                                                float* __restrict__ wts, int nsp) {
    const int gidx = blockIdx.x * 256 + threadIdx.x;   // b*16384 + h*1024+d*32+e
    float s = 0.f;
#pragma unroll 8
    for (int pp = 0; pp < nsp; ++pp)
        s += part[((size_t)pp << 18) + gidx];
    wts[gidx] = s * (1.0f / 64.0f);                    // / sqrt(4096)
}

// ---------------- Kernel B2: softmax over batch axis (R12-proven) ----------------
__global__ __launch_bounds__(256) void softmax_b(float* __restrict__ wts) {
    const int idx = blockIdx.x * 256 + threadIdx.x;    // 0..16383

    float sc[BS];
#pragma unroll
    for (int b = 0; b < BS; ++b) sc[b] = wts[((size_t)b << 14) + idx];
    float m = sc[0];
#pragma unroll
    for (int b = 1; b < BS; ++b) m = fmaxf(m, sc[b]);
    float sum = 0.f;
#pragma unroll
    for (int b = 0; b < BS; ++b) { sc[b] = __expf(sc[b] - m); sum += sc[b]; }
    const float inv = 1.0f / sum;
#pragma unroll
    for (int b = 0; b < BS; ++b) wts[((size_t)b << 14) + idx] = sc[b] * inv;
}

// ---------------- Kernel C: out = Q @ W (R12-proven, ~26us) ----------------
__global__ __launch_bounds__(256, 2) void qw(const float* __restrict__ q,
                                             const float* __restrict__ wts,
                                             float* __restrict__ out) {
    __shared__ float qs[128 * 36];
    const int blk = blockIdx.x;
    const int bh  = blk >> 5;
    const int lt  = blk & 31;
    const int tid = threadIdx.x;

    const float* qbase = q + ((size_t)bh * LQ + lt * 128) * DH;

#pragma unroll
    for (int pp = 0; pp < 4; ++pp) {
        const int idx = pp * 256 + tid;           // float4 index 0..1023
        const int row = idx >> 3;
        const int c4  = idx & 7;
        const float4 t = *(const float4*)(qbase + idx * 4);
        *(float4*)(qs + row * 36 + c4 * 4) = t;
    }

    const int lsub = tid >> 3;                    // 0..31
    const int e0   = (tid & 7) << 2;

    // wts layout [b][h][d][e]: base = b*16384 + h*1024
    const int b = bh >> 4, h = bh & 15;
    float4 Wf[32];
    const float* wbase = wts + ((size_t)b << 14) + ((size_t)h << 10) + e0;
#pragma unroll
    for (int d = 0; d < 32; ++d) Wf[d] = *(const float4*)(wbase + d * DH);

    __syncthreads();

    float* obase = out + ((size_t)bh * LQ + lt * 128) * DH;

#pragma unroll
    for (int r = 0; r < 4; ++r) {
        const int lr = lsub + r * 32;
        const float* qrow = qs + lr * 36;
        float4 acc = {0, 0, 0, 0};
#pragma unroll
        for (int d4 = 0; d4 < 32; d4 += 4) {
            const float4 qv = *(const float4*)(qrow + d4);
            fma4(acc, qv.x, Wf[d4 + 0]);
            fma4(acc, qv.y, Wf[d4 + 1]);
            fma4(acc, qv.z, Wf[d4 + 2]);
            fma4(acc, qv.w, Wf[d4 + 3]);
        }
        *(float4*)(obase + (size_t)lr * DH + e0) = acc;
    }
}

extern "C" void kernel_launch(void* const* d_in, const int* in_sizes, int n_in,
                              void* d_out, int out_size, void* d_ws, size_t ws_size,
                              hipStream_t stream) {
    const float* q = (const float*)d_in[0];
    const float* k = (const float*)d_in[1];
    const float* v = (const float*)d_in[2];
    float* out  = (float*)d_out;
    float* wts  = out + OUT_ELEMS;          // attn_weights region of d_out
    float* part = (float*)d_ws;

    const size_t need32 = (size_t)32 * 256 * 1024 * 4;   // 33.55 MB of partials
    int nsp;
    if (ws_size >= need32) {
        kv_partial<4><<<256 * 32, 64, 0, stream>>>(k, v, part);    // 8192 blocks
        nsp = 32;
    } else {
        kv_partial<16><<<256 * 8, 64, 0, stream>>>(k, v, part);    // 2048 blocks
        nsp = 8;
    }
    reduce_p<<<(BS * HDE) / 256, 256, 0, stream>>>(part, wts, nsp);
    softmax_b<<<HDE / 256, 256, 0, stream>>>(wts);
    qw<<<BS * NH * (LQ / 128), 256, 0, stream>>>(q, wts, out);
}

// Round 21
// 140.914 us; speedup vs baseline: 1.2612x; 1.0014x over previous
//
#include <hip/hip_runtime.h>

#define BS 16
#define NH 16
#define LQ 4096
#define DH 32

constexpr size_t OUT_ELEMS = (size_t)BS * NH * LQ * DH;   // 33,554,432
constexpr int HDE = NH * DH * DH;           // 16384

// global -> LDS direct copy, 16 B per lane. dst is the WAVE-UNIFORM base;
// HW writes dst + lane*16. src is per-lane.
__device__ __forceinline__ void async_cp16(float* dst, const float* src) {
    __builtin_amdgcn_global_load_lds(
        (const __attribute__((address_space(1))) void*)src,
        (__attribute__((address_space(3))) void*)dst, 16, 0, 0);
}

// full vmem drain + compiler fence: no memory op (ds_read/gll) crosses this.
__device__ __forceinline__ void vmfence() {
    asm volatile("s_waitcnt vmcnt(0)" ::: "memory");
    __builtin_amdgcn_sched_barrier(0);
}

__device__ __forceinline__ void fma4(float4& a, float s, const float4& v) {
    a.x = fmaf(s, v.x, a.x);
    a.y = fmaf(s, v.y, a.y);
    a.z = fmaf(s, v.z, a.z);
    a.w = fmaf(s, v.w, a.w);
}

// ---------------- Kernel A: partial K@V — independent-wave gll pipeline ----------------
// R2-R20 synthesis: the 95-105us invariant = 48 ds_read_b128/wave-window
// (~61us chip LDS-pipe) + per-window-serialized fill latency. Fix both:
// (1) 8d x 8e lane tile (16 lanes cover W, sp = l>>4 quarter-splits s):
//     32 b128/window -> ~41us LDS total; K slot c^(r>>3), V chunk-slot
//     g^perm(s>>2) with perm(y)=(y>>1)|((y&1)<<2) -- both derived 2-way
//     balanced over the 8 bank-quads (2-way = free, m136).
// (2) 4 FULLY-INDEPENDENT waves/block (zero barriers anywhere), wave-private
//     DOUBLE-BUFFERED LDS filled via gll (no regs held -> no spill), pipeline
//     fill(c+1) -> compute(c) -> vmcnt(0) FULL drain. No counted vmcnt (R3/4/6
//     failures), no cross-wave visibility: WAR/RAW safe by program order +
//     full drains (fill(c+1) lands >=300cy after issue, which is after
//     compute(c-1)'s reads were consumed; compute(c+1) reads only after the
//     drain that covers fill(c+1)).
// LDS 4 waves x 2 buf x 8KB = 64KB -> 2 blocks/CU = 8 waves/CU; per-CU LDS
// demand 8x384cy vs VALU 2048cy/SIMD -> ~67% VALU util target.
template<int NWIN>   // 32-s windows per wave
__global__ __launch_bounds__(256, 2) void kv_partial(const float* __restrict__ k,
                                                     const float* __restrict__ v,
                                                     float* __restrict__ part) {
    __shared__ float lds[16384];            // wave w owns [w*4096, (w+1)*4096)
    const int tid = threadIdx.x;
    const int w   = tid >> 6;
    const int l   = tid & 63;
    const int nsplit = 128 / NWIN;          // wave covers NWIN*32 s
    const int task = blockIdx.x * 4 + w;    // 4 independent waves per block
    const int p  = task % nsplit;
    const int bh = task / nsplit;

    const int sp = l >> 4;                  // 0..3: s-quarter of each window
    const int dg = (l >> 2) & 3;            // 0..3: 8-row group
    const int eg = l & 3;                   // 0..3: 8-col group
    const int d0 = dg << 3;
    const int e0g = eg << 1;                // first e-chunk (4-float units)

    const float* kb = k + (size_t)bh * DH * LQ;
    const float* vb = v + (size_t)bh * LQ * DH;
    float* wlds = lds + (w << 12);

    // gll source offsets (window-invariant). K gll j: lane -> row r=8j+(l>>3),
    // store slot cs=l&7 holds chunk cs^j (r>>3=j). V gll m: lane -> row
    // s=8m+(l>>3), slot gs=l&7 holds chunk gs^perm(s>>2), perm(2m+(l>>5)) =
    // m + 4*(l>>5).
    size_t kgsrc[4], vgsrc[4];
#pragma unroll
    for (int j = 0; j < 4; ++j) {
        const int r = (j << 3) + (l >> 3);
        kgsrc[j] = (size_t)r * LQ + (((l & 7) ^ j) << 2);
        const int g = (l & 7) ^ (j + ((l >> 5) << 2));
        vgsrc[j] = ((size_t)((j << 3) + (l >> 3)) << 5) + (g << 2);
    }

    float4 acc[8][2];
#pragma unroll
    for (int i = 0; i < 8; ++i) {
        acc[i][0] = make_float4(0.f, 0.f, 0.f, 0.f);
        acc[i][1] = make_float4(0.f, 0.f, 0.f, 0.f);
    }

#define FILL(c_) do {                                                          \
        float* kt_ = wlds + (((c_) & 1) << 11);                                \
        float* vt_ = kt_ + 1024;                                               \
        const int wb_ = (p * NWIN + (c_)) << 5;                                \
        _Pragma("unroll")                                                      \
        for (int j = 0; j < 4; ++j)                                            \
            async_cp16(kt_ + (j << 8), kb + kgsrc[j] + wb_);                   \
        _Pragma("unroll")                                                      \
        for (int j = 0; j < 4; ++j)                                            \
            async_cp16(vt_ + (j << 8), vb + vgsrc[j] + ((size_t)wb_ << 5));    \
    } while (0)

    FILL(0);
    vmfence();                              // buf0 resident (one-time prologue)

#pragma unroll
    for (int c = 0; c < NWIN; ++c) {
        if (c + 1 < NWIN) FILL(c + 1);      // flies during compute(c)

        const float* kt = wlds + ((c & 1) << 11);
        const float* vt = kt + 1024;
#pragma unroll
        for (int it = 0; it < 2; ++it) {
            const int cc  = (sp << 1) + it;             // s-chunk 0..7 (4 s)
            const int pcc = (cc >> 1) | ((cc & 1) << 2);
            float4 kq[8];
#pragma unroll
            for (int i = 0; i < 8; ++i)
                kq[i] = *(const float4*)(kt + ((d0 + i) << 5) + (((cc ^ dg) & 7) << 2));
#pragma unroll
            for (int u = 0; u < 4; ++u) {
                const int s = (cc << 2) + u;
                const float4 vu0 = *(const float4*)(vt + (s << 5) + (((e0g ^ pcc) & 7) << 2));
                const float4 vu1 = *(const float4*)(vt + (s << 5) + ((((e0g | 1) ^ pcc) & 7) << 2));
#pragma unroll
                for (int i = 0; i < 8; ++i) {
                    const float ks = (u == 0) ? kq[i].x
                                   : (u == 1) ? kq[i].y
                                   : (u == 2) ? kq[i].z : kq[i].w;
                    fma4(acc[i][0], ks, vu0);
                    fma4(acc[i][1], ks, vu1);
                }
            }
        }
        vmfence();                          // buf[(c+1)&1] resident; WAR ordered
    }
#undef FILL

    // reduce over the 4 sp-quarters: butterfly lane^16 then lane^32
#pragma unroll
    for (int i = 0; i < 8; ++i)
#pragma unroll
        for (int h = 0; h < 2; ++h) {
            acc[i][h].x += __shfl_xor(acc[i][h].x, 16);
            acc[i][h].y += __shfl_xor(acc[i][h].y, 16);
            acc[i][h].z += __shfl_xor(acc[i][h].z, 16);
            acc[i][h].w += __shfl_xor(acc[i][h].w, 16);
            acc[i][h].x += __shfl_xor(acc[i][h].x, 32);
            acc[i][h].y += __shfl_xor(acc[i][h].y, 32);
            acc[i][h].z += __shfl_xor(acc[i][h].z, 32);
            acc[i][h].w += __shfl_xor(acc[i][h].w, 32);
        }

    // sp==0 lanes (16) store their 8x8 tile; static indices only (rule #20)
    if (sp == 0) {
        float* pb = part + (((size_t)p << 8) + bh) * 1024;
#pragma unroll
        for (int i = 0; i < 8; ++i) {
            *(float4*)(pb + ((d0 + i) << 5) + (e0g << 2))     = acc[i][0];
            *(float4*)(pb + ((d0 + i) << 5) + (e0g << 2) + 4) = acc[i][1];
        }
    }
}

// ---------------- Kernel B1: reduce partials over p (R12-proven) ----------------
__global__ __launch_bounds__(256) void reduce_p(const float* __restrict__ part,
                                                float* __restrict__ wts, int nsp) {
    const int gidx = blockIdx.x * 256 + threadIdx.x;   // b*16384 + h*1024+d*32+e
    float s = 0.f;
#pragma unroll 8
    for (int pp = 0; pp < nsp; ++pp)
        s += part[((size_t)pp << 18) + gidx];
    wts[gidx] = s * (1.0f / 64.0f);                    // / sqrt(4096)
}

// ---------------- Kernel B2: softmax over batch axis (R12-proven) ----------------
__global__ __launch_bounds__(256) void softmax_b(float* __restrict__ wts) {
    const int idx = blockIdx.x * 256 + threadIdx.x;    // 0..16383

    float sc[BS];
#pragma unroll
    for (int b = 0; b < BS; ++b) sc[b] = wts[((size_t)b << 14) + idx];
    float m = sc[0];
#pragma unroll
    for (int b = 1; b < BS; ++b) m = fmaxf(m, sc[b]);
    float sum = 0.f;
#pragma unroll
    for (int b = 0; b < BS; ++b) { sc[b] = __expf(sc[b] - m); sum += sc[b]; }
    const float inv = 1.0f / sum;
#pragma unroll
    for (int b = 0; b < BS; ++b) wts[((size_t)b << 14) + idx] = sc[b] * inv;
}

// ---------------- Kernel C: out = Q @ W (R12-proven, ~26us) ----------------
__global__ __launch_bounds__(256, 2) void qw(const float* __restrict__ q,
                                             const float* __restrict__ wts,
                                             float* __restrict__ out) {
    __shared__ float qs[128 * 36];
    const int blk = blockIdx.x;
    const int bh  = blk >> 5;
    const int lt  = blk & 31;
    const int tid = threadIdx.x;

    const float* qbase = q + ((size_t)bh * LQ + lt * 128) * DH;

#pragma unroll
    for (int pp = 0; pp < 4; ++pp) {
        const int idx = pp * 256 + tid;           // float4 index 0..1023
        const int row = idx >> 3;
        const int c4  = idx & 7;
        const float4 t = *(const float4*)(qbase + idx * 4);
        *(float4*)(qs + row * 36 + c4 * 4) = t;
    }

    const int lsub = tid >> 3;                    // 0..31
    const int e0   = (tid & 7) << 2;

    // wts layout [b][h][d][e]: base = b*16384 + h*1024
    const int b = bh >> 4, h = bh & 15;
    float4 Wf[32];
    const float* wbase = wts + ((size_t)b << 14) + ((size_t)h << 10) + e0;
#pragma unroll
    for (int d = 0; d < 32; ++d) Wf[d] = *(const float4*)(wbase + d * DH);

    __syncthreads();

    float* obase = out + ((size_t)bh * LQ + lt * 128) * DH;

#pragma unroll
    for (int r = 0; r < 4; ++r) {
        const int lr = lsub + r * 32;
        const float* qrow = qs + lr * 36;
        float4 acc = {0, 0, 0, 0};
#pragma unroll
        for (int d4 = 0; d4 < 32; d4 += 4) {
            const float4 qv = *(const float4*)(qrow + d4);
            fma4(acc, qv.x, Wf[d4 + 0]);
            fma4(acc, qv.y, Wf[d4 + 1]);
            fma4(acc, qv.z, Wf[d4 + 2]);
            fma4(acc, qv.w, Wf[d4 + 3]);
        }
        *(float4*)(obase + (size_t)lr * DH + e0) = acc;
    }
}

extern "C" void kernel_launch(void* const* d_in, const int* in_sizes, int n_in,
                              void* d_out, int out_size, void* d_ws, size_t ws_size,
                              hipStream_t stream) {
    const float* q = (const float*)d_in[0];
    const float* k = (const float*)d_in[1];
    const float* v = (const float*)d_in[2];
    float* out  = (float*)d_out;
    float* wts  = out + OUT_ELEMS;          // attn_weights region of d_out
    float* part = (float*)d_ws;

    const size_t need16 = (size_t)16 * 256 * 1024 * 4;   // 16.8 MB of partials
    int nsp;
    if (ws_size >= need16) {
        kv_partial<8><<<(256 * 16) / 4, 256, 0, stream>>>(k, v, part);   // 4096 waves
        nsp = 16;
    } else {
        kv_partial<16><<<(256 * 8) / 4, 256, 0, stream>>>(k, v, part);   // 2048 waves
        nsp = 8;
    }
    reduce_p<<<(BS * HDE) / 256, 256, 0, stream>>>(part, wts, nsp);
    softmax_b<<<HDE / 256, 256, 0, stream>>>(wts);
    qw<<<BS * NH * (LQ / 128), 256, 0, stream>>>(q, wts, out);
}